// Round 5
// baseline (2382.380 us; speedup 1.0000x reference)
//
#include <hip/hip_runtime.h>
#include <stdint.h>

// GRU: B=64, T=1024, I=256, H=256, fp32 in/out, bf16 MFMA compute.
// k_prep: fragmentize 6 weight mats into MFMA B-frag layout; fold biases.
// k_proj: x_m = X@W_m + b'_m (z,r pre-scaled by -log2 e), D-frag 8B chunks.
// k_rnn : 16 blocks x 1024 thr (16 waves, 4/SIMD); 4 batches/block (rows 0-3
//         of the M=16 tile). Each wave owns ONE 16-col n-tile; ALL THREE
//         U-mat n-tile B-frags live in registers/AGPRs (96 regs) -> zero
//         weight LDS traffic. hb stores only rows 0-3 (2KB/buf); lanes with
//         (l&15)>=4 use constant-zero A-frags (no LDS read). One gate
//         output per lane via wave-private G redistribution. Light barrier
//         (lgkmcnt-only) per step.

typedef float  f32x4 __attribute__((ext_vector_type(4)));
typedef short  s16x8 __attribute__((ext_vector_type(8)));
typedef unsigned short u16;

#define MFMA_BF16(a, b, c) __builtin_amdgcn_mfma_f32_16x16x32_bf16((a), (b), (c), 0, 0, 0)
#define L2E 1.4426950408889634f

static __device__ __forceinline__ u16 f2bf(float f) {
  uint32_t u = __float_as_uint(f);
  u += 0x7FFFu + ((u >> 16) & 1u);   // RNE
  return (u16)(u >> 16);
}
static __device__ __forceinline__ uint32_t cvt_pk_bf16(float lo, float hi) {
  uint32_t r;
  asm("v_cvt_pk_bf16_f32 %0, %1, %2" : "=v"(r) : "v"(lo), "v"(hi));
  return r;
}
static __device__ __forceinline__ float fast_exp2(float x) {
#if __has_builtin(__builtin_amdgcn_exp2f)
  return __builtin_amdgcn_exp2f(x);
#else
  return exp2f(x);
#endif
}
static __device__ __forceinline__ float fast_rcp(float x) {
#if __has_builtin(__builtin_amdgcn_rcpf)
  return __builtin_amdgcn_rcpf(x);
#else
  return 1.0f / x;
#endif
}
static __device__ __forceinline__ float tanh_(float x) {
  float ax = fabsf(x);
  float e  = fast_exp2(-2.885390081777927f * ax);   // exp(-2|x|)
  float r  = (1.0f - e) * fast_rcp(1.0f + e);
  return x < 0.0f ? -r : r;
}

// ---- ws layout (bytes) ----
// [0, 786432)          : 6 mats x 8kk x 16n x 64lane x 16B bf16 B-fragments
// [786432, 789504)     : folded biases, 3 x 256 fp32 (unscaled)
// [1MiB, 1MiB + 96MiB) : x projections bf16, [m][t][g][n][lane] 8B chunks
#define WS_BIAS_OFF  786432
#define WS_X_OFF     (1u << 20)

// Fragment convention: kappa(l,i) = (l>>4)*8 + i.
// B-frag (mat,kk,n): lane l slot i = M[32kk + kappa(l,i)][16n + (l&15)]
// A-frag (kk):       lane l slot i = A[l&15][32kk + kappa(l,i)]
// C/D: col = lane&15, row = (lane>>4)*4 + reg   [m89]
// hb2 (rows 0-3 only): value (row r, feature f) -> byte
//   (f>>5)*256 + r*64 + ((f>>3)&3)*16 + (f&7)*2
//   reader lane l (act = (l&15)<4): 16B at (l&15)*64 + (l>>4)*16 + kk*256

__global__ __launch_bounds__(256) void k_prep(
    const float* __restrict__ Wz, const float* __restrict__ Wr, const float* __restrict__ Wh,
    const float* __restrict__ Uz, const float* __restrict__ Ur, const float* __restrict__ Uh,
    const float* __restrict__ bz, const float* __restrict__ br, const float* __restrict__ bh,
    const float* __restrict__ cz, const float* __restrict__ cr, const float* __restrict__ ch,
    u16* __restrict__ wfrag, float* __restrict__ wbias)
{
  if (blockIdx.x == 192) {   // bias fold block
    int c = threadIdx.x;
    wbias[c]       = bz[c] + cz[c];
    wbias[256 + c] = br[c] + cr[c];
    wbias[512 + c] = bh[c];
    return;
  }
  int tid = blockIdx.x * 256 + threadIdx.x;      // 0..49151
  int mat = tid >> 13;                           // 6 mats x 8192 threads
  int kk  = (tid >> 10) & 7;
  int n   = (tid >> 6) & 15;
  int l   = tid & 63;
  const float* M = (mat == 0) ? Wz : (mat == 1) ? Wr : (mat == 2) ? Wh
                 : (mat == 3) ? Uz : (mat == 4) ? Ur : Uh;
  int col   = n * 16 + (l & 15);
  int kbase = kk * 32 + (l >> 4) * 8;
  uint32_t d[4];
#pragma unroll
  for (int p = 0; p < 4; ++p) {
    u16 lo = f2bf(M[(kbase + 2 * p    ) * 256 + col]);
    u16 hi = f2bf(M[(kbase + 2 * p + 1) * 256 + col]);
    d[p] = (uint32_t)lo | ((uint32_t)hi << 16);
  }
  uint32_t* dst = (uint32_t*)(wfrag + ((size_t)mat * 65536 + (size_t)((kk * 16 + n) * 64 + l) * 8));
  dst[0] = d[0]; dst[1] = d[1]; dst[2] = d[2]; dst[3] = d[3];
}

__global__ __launch_bounds__(256) void k_proj(
    const float* __restrict__ X, const u16* __restrict__ wfrag,
    const float* __restrict__ wbias, u16* __restrict__ xout)
{
  const int t   = blockIdx.x;
  const int tid = threadIdx.x;
  const int l   = tid & 63;
  const int w   = tid >> 6;        // wave = batch group (M-tile)

  // A-fragments straight from global: row b = 16w + (l&15), k = 32kk + (l>>4)*8 + i
  const float* xrow = X + ((size_t)(w * 16 + (l & 15)) * 1024 + t) * 256 + (l >> 4) * 8;
  s16x8 af[8];
#pragma unroll
  for (int kk = 0; kk < 8; ++kk) {
    f32x4 a0 = *(const f32x4*)(xrow + kk * 32);
    f32x4 a1 = *(const f32x4*)(xrow + kk * 32 + 4);
    union { uint32_t d[4]; s16x8 v; } U;
    U.d[0] = cvt_pk_bf16(a0[0], a0[1]);
    U.d[1] = cvt_pk_bf16(a0[2], a0[3]);
    U.d[2] = cvt_pk_bf16(a1[0], a1[1]);
    U.d[3] = cvt_pk_bf16(a1[2], a1[3]);
    af[kk] = U.v;
  }

  const s16x8* WB = (const s16x8*)wfrag;
  const int g = w;
#pragma unroll
  for (int m = 0; m < 3; ++m) {
    f32x4 acc[16];
#pragma unroll
    for (int n = 0; n < 16; ++n) acc[n] = 0.0f;
#pragma unroll
    for (int kk = 0; kk < 8; ++kk) {
#pragma unroll
      for (int n = 0; n < 16; ++n) {
        s16x8 bf = WB[(size_t)m * 8192 + (kk * 16 + n) * 64 + l];
        acc[n] = MFMA_BF16(af[kk], bf, acc[n]);
      }
    }
    const float scale = (m < 2) ? -L2E : 1.0f;   // pre-scale z,r by -log2(e)
#pragma unroll
    for (int n = 0; n < 16; ++n) {
      int col = n * 16 + (l & 15);
      float b = wbias[m * 256 + col];
      float v0 = (acc[n][0] + b) * scale;
      float v1 = (acc[n][1] + b) * scale;
      float v2 = (acc[n][2] + b) * scale;
      float v3 = (acc[n][3] + b) * scale;
      uint32_t w0 = cvt_pk_bf16(v0, v1);
      uint32_t w1 = cvt_pk_bf16(v2, v3);
      size_t idx = ((((size_t)m * 1024 + t) * 4 + g) * 16 + n) * 64 + l;
      ((uint64_t*)xout)[idx] = (uint64_t)w0 | ((uint64_t)w1 << 32);
    }
  }
}

__global__ __launch_bounds__(1024) void k_rnn(
    const u16* __restrict__ wfrag, const u16* __restrict__ xin,
    const float* __restrict__ h0, const float* __restrict__ ch,
    float* __restrict__ out)
{
  __shared__ __align__(16) u16 hb2[2][1024];        // 2 x 2 KiB h A-frags (rows 0-3)
  __shared__ __align__(16) float G[16][3][16][4];   // 12 KiB wave-private D redistribution

  const int blk = blockIdx.x;           // 0..15 ; batches [4*blk, 4*blk+4)
  const int g   = blk >> 2;             // 16-batch group (xbuf layout)
  const int q   = blk & 3;              // quarter within group
  const int tid = threadIdx.x;
  const int l   = tid & 63;
  const int w   = tid >> 6;             // wave 0..15 owns cols [16w, 16w+16)

  const int col16 = l & 15;
  const int r4    = l >> 4;             // this lane's batch row 0..3
  const int cgate = w * 16 + col16;     // global col of this lane's gate output

  const s16x8* WB = (const s16x8*)wfrag;

  // Uz, Ur, Uh register fragments for n-tile w (96 regs; compiler -> AGPR)
  s16x8 BZ[8], BR[8], BH[8];
#pragma unroll
  for (int kk = 0; kk < 8; ++kk) {
    BZ[kk] = WB[(size_t)3 * 8192 + (kk * 16 + w) * 64 + l];
    BR[kk] = WB[(size_t)4 * 8192 + (kk * 16 + w) * 64 + l];
    BH[kk] = WB[(size_t)5 * 8192 + (kk * 16 + w) * 64 + l];
  }

  // h master (fp32) for this lane's output + ch
  const float chv = ch[cgate];
  float hp = h0[(size_t)(4 * blk + r4) * 256 + cgate];

  // hb2 byte offsets
  char* hbbase = (char*)&hb2[0][0];
  const int wb_off = ((w >> 1) * 256) + r4 * 64 +
                     ((((w & 1) << 1) | (col16 >> 3)) * 16) + ((col16 & 7) * 2);
  const int rd_off = (l & 15) * 64 + (l >> 4) * 16;
  const bool act   = (l & 15) < 4;

  // seed buffer 0
  *(u16*)(hbbase + wb_off) = f2bf(hp);
  __syncthreads();

  // u16-element offsets into xbuf (shared SGPR base, u32 voffsets)
  uint32_t xo = 4u * (uint32_t)(g * 1024 + w * 64 + 16 * q + col16) + (uint32_t)r4;
  uint32_t oo = (uint32_t)(4 * blk + r4) * 262144u + (uint32_t)cgate;

  int hoff = 0;

  for (int t = 0; t < 1024; ++t) {
    // per-lane x values (bf16 as u16), issued early
    u16 x0 = xin[xo];
    u16 x1 = xin[xo + 16777216u];
    u16 x2 = xin[xo + 33554432u];
    xo += 16384u;

    const char* hbr = hbbase + hoff + rd_off;

    // ---- MFMA phase: 3 mats x 8 kk; only lanes with (l&15)<4 read LDS ----
    f32x4 az = 0.0f, ar = 0.0f, ah = 0.0f;
#pragma unroll
    for (int kk = 0; kk < 8; ++kk) {
      s16x8 a_ = (s16x8)0;
      if (act) a_ = *(const s16x8*)(hbr + kk * 256);
      az = MFMA_BF16(a_, BZ[kk], az);
      ar = MFMA_BF16(a_, BR[kk], ar);
      ah = MFMA_BF16(a_, BH[kk], ah);
    }

    // ---- wave-private redistribution (lanes 0-15 hold rows 0-3) ----
    if (l < 16) {
      *(f32x4*)&G[w][0][l][0] = az;
      *(f32x4*)&G[w][1][l][0] = ar;
      *(f32x4*)&G[w][2][l][0] = ah;
    }
    float vz = G[w][0][col16][r4];
    float vr = G[w][1][col16][r4];
    float vh = G[w][2][col16][r4];

    // ---- gate: 1 output per lane ----
    float xz = __uint_as_float((uint32_t)x0 << 16);
    float xr = __uint_as_float((uint32_t)x1 << 16);
    float xh = __uint_as_float((uint32_t)x2 << 16);

    float z  = fast_rcp(1.0f + fast_exp2(fmaf(vz, -L2E, xz)));
    float rg = fast_rcp(1.0f + fast_exp2(fmaf(vr, -L2E, xr)));
    float th = tanh_(fmaf(rg, vh + chv, xh));
    float hn = fmaf(z, hp - th, th);
    hp = hn;

    // next-step A-frag write + output store (store stays in flight)
    *(u16*)(hbbase + (hoff ^ 2048) + wb_off) = f2bf(hn);
    out[oo] = hn;
    oo += 256u;

    hoff ^= 2048;
    // light barrier: LDS ordering only; do NOT drain vmcnt (out stores)
    asm volatile("s_waitcnt lgkmcnt(0)" ::: "memory");
    __builtin_amdgcn_s_barrier();
  }

  // h_last
  out[16777216u + (uint32_t)(4 * blk + r4) * 256u + (uint32_t)cgate] = hp;
}

extern "C" void kernel_launch(void* const* d_in, const int* in_sizes, int n_in,
                              void* d_out, int out_size, void* d_ws, size_t ws_size,
                              hipStream_t stream) {
  const float* X  = (const float*)d_in[0];
  const float* h0 = (const float*)d_in[1];
  const float* Wz = (const float*)d_in[2];
  const float* Wr = (const float*)d_in[3];
  const float* Wh = (const float*)d_in[4];
  const float* bz = (const float*)d_in[5];
  const float* br = (const float*)d_in[6];
  const float* bh = (const float*)d_in[7];
  const float* Uz = (const float*)d_in[8];
  const float* Ur = (const float*)d_in[9];
  const float* Uh = (const float*)d_in[10];
  const float* cz = (const float*)d_in[11];
  const float* cr = (const float*)d_in[12];
  const float* ch = (const float*)d_in[13];

  char*  ws    = (char*)d_ws;
  u16*   wfrag = (u16*)ws;
  float* wbias = (float*)(ws + WS_BIAS_OFF);
  u16*   xbuf  = (u16*)(ws + WS_X_OFF);
  float* out   = (float*)d_out;

  k_prep<<<193, 256, 0, stream>>>(Wz, Wr, Wh, Uz, Ur, Uh, bz, br, bh, cz, cr, ch,
                                  wfrag, wbias);
  k_proj<<<1024, 256, 0, stream>>>(X, wfrag, wbias, xbuf);
  k_rnn<<<16, 1024, 0, stream>>>(wfrag, xbuf, h0, ch, out);
}

// Round 6
// 1294.902 us; speedup vs baseline: 1.8398x; 1.8398x over previous
//
#include <hip/hip_runtime.h>
#include <stdint.h>

// GRU: B=64, T=1024, I=256, H=256, fp32 in/out, bf16 MFMA compute.
// k_prep: fragmentize 6 weight mats into MFMA B-frag layout; fold biases.
// k_proj: x_m = X@W_m + b'_m (z,r pre-scaled by -log2 e), D-frag 8B chunks.
// k_rnn : 32 blocks x 512 thr (8 waves, 2/SIMD -> 256-reg budget); 2 batches
//         per block (rows 0-1 of the M=16 tile). Each wave owns TWO 16-col
//         n-tiles; ALL THREE U-mat B-frags in registers (48 x s16x8 = 192
//         regs, fits the 2-wave/SIMD budget -> no reload/spill, the R5 bug).
//         h A-frags: unconditional ds_read_b128; the 56 lanes with
//         (l&15)>=2 read a 512B all-zero LDS pad (same addr -> broadcast).
//         One gate output per lane via wave-private G redistribution.
//         Light barrier (lgkmcnt-only) per step; x prefetched 1 step ahead.

typedef float  f32x4 __attribute__((ext_vector_type(4)));
typedef float  f32x2 __attribute__((ext_vector_type(2)));
typedef short  s16x8 __attribute__((ext_vector_type(8)));
typedef unsigned short u16;

#define MFMA_BF16(a, b, c) __builtin_amdgcn_mfma_f32_16x16x32_bf16((a), (b), (c), 0, 0, 0)
#define L2E 1.4426950408889634f

static __device__ __forceinline__ u16 f2bf(float f) {
  uint32_t u = __float_as_uint(f);
  u += 0x7FFFu + ((u >> 16) & 1u);   // RNE
  return (u16)(u >> 16);
}
static __device__ __forceinline__ uint32_t cvt_pk_bf16(float lo, float hi) {
  uint32_t r;
  asm("v_cvt_pk_bf16_f32 %0, %1, %2" : "=v"(r) : "v"(lo), "v"(hi));
  return r;
}
static __device__ __forceinline__ float fast_exp2(float x) {
#if __has_builtin(__builtin_amdgcn_exp2f)
  return __builtin_amdgcn_exp2f(x);
#else
  return exp2f(x);
#endif
}
static __device__ __forceinline__ float fast_rcp(float x) {
#if __has_builtin(__builtin_amdgcn_rcpf)
  return __builtin_amdgcn_rcpf(x);
#else
  return 1.0f / x;
#endif
}
static __device__ __forceinline__ float tanh_(float x) {
  float ax = fabsf(x);
  float e  = fast_exp2(-2.885390081777927f * ax);   // exp(-2|x|)
  float r  = (1.0f - e) * fast_rcp(1.0f + e);
  return x < 0.0f ? -r : r;
}

// ---- ws layout (bytes) ----
// [0, 786432)          : 6 mats x 8kk x 16n x 64lane x 16B bf16 B-fragments
// [786432, 789504)     : folded biases, 3 x 256 fp32 (unscaled)
// [1MiB, 1MiB + 96MiB) : x projections bf16, [m][t][g][n][lane] 8B chunks
#define WS_BIAS_OFF  786432
#define WS_X_OFF     (1u << 20)

// Fragment convention: kappa(l,i) = (l>>4)*8 + i.
// B-frag (mat,kk,n): lane l slot i = M[32kk + kappa(l,i)][16n + (l&15)]
// A-frag (kk):       lane l slot i = A[l&15][32kk + kappa(l,i)]
// C/D: col = lane&15, row = (lane>>4)*4 + reg   [m89]
// hb2 (rows 0-1 only): value (row r, feature f) -> byte r*512 + 2f.
//   active reader lane l ((l&15)<2): 16B at (l&15)*512 + (l>>4)*16 + kk*64.

__global__ __launch_bounds__(256) void k_prep(
    const float* __restrict__ Wz, const float* __restrict__ Wr, const float* __restrict__ Wh,
    const float* __restrict__ Uz, const float* __restrict__ Ur, const float* __restrict__ Uh,
    const float* __restrict__ bz, const float* __restrict__ br, const float* __restrict__ bh,
    const float* __restrict__ cz, const float* __restrict__ cr, const float* __restrict__ ch,
    u16* __restrict__ wfrag, float* __restrict__ wbias)
{
  if (blockIdx.x == 192) {   // bias fold block
    int c = threadIdx.x;
    wbias[c]       = bz[c] + cz[c];
    wbias[256 + c] = br[c] + cr[c];
    wbias[512 + c] = bh[c];
    return;
  }
  int tid = blockIdx.x * 256 + threadIdx.x;      // 0..49151
  int mat = tid >> 13;                           // 6 mats x 8192 threads
  int kk  = (tid >> 10) & 7;
  int n   = (tid >> 6) & 15;
  int l   = tid & 63;
  const float* M = (mat == 0) ? Wz : (mat == 1) ? Wr : (mat == 2) ? Wh
                 : (mat == 3) ? Uz : (mat == 4) ? Ur : Uh;
  int col   = n * 16 + (l & 15);
  int kbase = kk * 32 + (l >> 4) * 8;
  uint32_t d[4];
#pragma unroll
  for (int p = 0; p < 4; ++p) {
    u16 lo = f2bf(M[(kbase + 2 * p    ) * 256 + col]);
    u16 hi = f2bf(M[(kbase + 2 * p + 1) * 256 + col]);
    d[p] = (uint32_t)lo | ((uint32_t)hi << 16);
  }
  uint32_t* dst = (uint32_t*)(wfrag + ((size_t)mat * 65536 + (size_t)((kk * 16 + n) * 64 + l) * 8));
  dst[0] = d[0]; dst[1] = d[1]; dst[2] = d[2]; dst[3] = d[3];
}

__global__ __launch_bounds__(256) void k_proj(
    const float* __restrict__ X, const u16* __restrict__ wfrag,
    const float* __restrict__ wbias, u16* __restrict__ xout)
{
  const int t   = blockIdx.x;
  const int tid = threadIdx.x;
  const int l   = tid & 63;
  const int w   = tid >> 6;        // wave = batch group (M-tile)

  // A-fragments straight from global: row b = 16w + (l&15), k = 32kk + (l>>4)*8 + i
  const float* xrow = X + ((size_t)(w * 16 + (l & 15)) * 1024 + t) * 256 + (l >> 4) * 8;
  s16x8 af[8];
#pragma unroll
  for (int kk = 0; kk < 8; ++kk) {
    f32x4 a0 = *(const f32x4*)(xrow + kk * 32);
    f32x4 a1 = *(const f32x4*)(xrow + kk * 32 + 4);
    union { uint32_t d[4]; s16x8 v; } U;
    U.d[0] = cvt_pk_bf16(a0[0], a0[1]);
    U.d[1] = cvt_pk_bf16(a0[2], a0[3]);
    U.d[2] = cvt_pk_bf16(a1[0], a1[1]);
    U.d[3] = cvt_pk_bf16(a1[2], a1[3]);
    af[kk] = U.v;
  }

  const s16x8* WB = (const s16x8*)wfrag;
  const int g = w;
#pragma unroll
  for (int m = 0; m < 3; ++m) {
    f32x4 acc[16];
#pragma unroll
    for (int n = 0; n < 16; ++n) acc[n] = 0.0f;
#pragma unroll
    for (int kk = 0; kk < 8; ++kk) {
#pragma unroll
      for (int n = 0; n < 16; ++n) {
        s16x8 bf = WB[(size_t)m * 8192 + (kk * 16 + n) * 64 + l];
        acc[n] = MFMA_BF16(af[kk], bf, acc[n]);
      }
    }
    const float scale = (m < 2) ? -L2E : 1.0f;   // pre-scale z,r by -log2(e)
#pragma unroll
    for (int n = 0; n < 16; ++n) {
      int col = n * 16 + (l & 15);
      float b = wbias[m * 256 + col];
      float v0 = (acc[n][0] + b) * scale;
      float v1 = (acc[n][1] + b) * scale;
      float v2 = (acc[n][2] + b) * scale;
      float v3 = (acc[n][3] + b) * scale;
      uint32_t w0 = cvt_pk_bf16(v0, v1);
      uint32_t w1 = cvt_pk_bf16(v2, v3);
      size_t idx = ((((size_t)m * 1024 + t) * 4 + g) * 16 + n) * 64 + l;
      ((uint64_t*)xout)[idx] = (uint64_t)w0 | ((uint64_t)w1 << 32);
    }
  }
}

__global__ __launch_bounds__(512, 2) void k_rnn(
    const u16* __restrict__ wfrag, const u16* __restrict__ xin,
    const float* __restrict__ h0, const float* __restrict__ ch,
    float* __restrict__ out)
{
  __shared__ __align__(16) u16 hb2[2][512];          // 2 x 1 KiB h rows 0-1 (dbuf)
  __shared__ __align__(16) u16 zpad[256];            // 512 B of zeros
  __shared__ __align__(16) float G[8][3][2][16][2];  // 6 KiB wave-private D redistribution

  const int blk = blockIdx.x;           // 0..31 ; batches 2*blk, 2*blk+1
  const int tid = threadIdx.x;
  const int l   = tid & 63;
  const int w   = tid >> 6;             // wave 0..7 owns cols [32w, 32w+32)

  const int col16 = l & 15;
  const int ntg   = (l >> 4) & 1;       // gate n-tile within wave
  const int rg    = l >> 5;             // gate batch row 0/1
  const int cg    = w * 32 + (l & 31);  // global col of this lane's gate output
  const int b     = 2 * blk + rg;       // global batch of this lane's output

  const s16x8* WB = (const s16x8*)wfrag;

  // All three U-mat B-frags for n-tiles 2w, 2w+1 in registers (192 regs)
  s16x8 BZ[2][8], BR[2][8], BH[2][8];
#pragma unroll
  for (int nt = 0; nt < 2; ++nt) {
    int n = 2 * w + nt;
#pragma unroll
    for (int kk = 0; kk < 8; ++kk) {
      BZ[nt][kk] = WB[(size_t)3 * 8192 + (kk * 16 + n) * 64 + l];
      BR[nt][kk] = WB[(size_t)4 * 8192 + (kk * 16 + n) * 64 + l];
      BH[nt][kk] = WB[(size_t)5 * 8192 + (kk * 16 + n) * 64 + l];
    }
  }

  // zero pad init
  if (tid < 128) ((uint32_t*)zpad)[tid] = 0u;

  // h master (fp32) for this lane's output + ch
  const float chv = ch[cg];
  float hp = h0[(size_t)b * 256 + cg];

  // hb2 offsets
  char* hbbase = (char*)&hb2[0][0];
  const int wb_off = rg * 512 + cg * 2;              // write: value (rg, cg)
  const bool act   = (l & 15) < 2;
  const char* rd_act = hbbase + (l & 15) * 512 + (l >> 4) * 16;
  const uint32_t hmask = act ? 0xFFFFFFFFu : 0u;     // inactive lanes never toggle

  // seed buffer 0 (fully written: 512 lanes x 1 u16 = whole buffer)
  *(u16*)(hbbase + wb_off) = f2bf(hp);
  __syncthreads();

  // xbuf u16-element offsets; lane reads x[m][t][b][cg]
  const int g_  = b >> 4;
  const int n_  = cg >> 4;
  const int q4  = (b & 15) >> 2;
  const int j_  = b & 3;
  uint32_t xo = (uint32_t)((((g_) * 16 + n_) * 64 + q4 * 16 + col16) * 4 + j_);
  uint32_t oo = (uint32_t)b * 262144u + (uint32_t)cg;

  // prefetch t=0
  u16 nx0 = xin[xo];
  u16 nx1 = xin[xo + 16777216u];
  u16 nx2 = xin[xo + 33554432u];

  int hoff = 0;

  for (int t = 0; t < 1024; ++t) {
    u16 x0 = nx0, x1 = nx1, x2 = nx2;
    // prefetch t+1 (clamped on last iter)
    xo += (t < 1023) ? 16384u : 0u;
    nx0 = xin[xo];
    nx1 = xin[xo + 16777216u];
    nx2 = xin[xo + 33554432u];

    const char* rdp = act ? (rd_act + (hoff & hmask)) : (const char*)zpad;

    // ---- MFMA phase: 3 mats x 2 n-tiles x 8 kk, unconditional A reads ----
    f32x4 az[2], ar[2], ah[2];
#pragma unroll
    for (int nt = 0; nt < 2; ++nt) { az[nt] = 0.0f; ar[nt] = 0.0f; ah[nt] = 0.0f; }
#pragma unroll
    for (int kk = 0; kk < 8; ++kk) {
      s16x8 a_ = *(const s16x8*)(rdp + kk * 64);
      az[0] = MFMA_BF16(a_, BZ[0][kk], az[0]);
      ar[0] = MFMA_BF16(a_, BR[0][kk], ar[0]);
      ah[0] = MFMA_BF16(a_, BH[0][kk], ah[0]);
      az[1] = MFMA_BF16(a_, BZ[1][kk], az[1]);
      ar[1] = MFMA_BF16(a_, BR[1][kk], ar[1]);
      ah[1] = MFMA_BF16(a_, BH[1][kk], ah[1]);
    }

    // ---- wave-private redistribution (lanes 0-15: rows 0,1 in regs 0,1) ----
    if (l < 16) {
#pragma unroll
      for (int nt = 0; nt < 2; ++nt) {
        *(f32x2*)&G[w][0][nt][l][0] = f32x2{az[nt][0], az[nt][1]};
        *(f32x2*)&G[w][1][nt][l][0] = f32x2{ar[nt][0], ar[nt][1]};
        *(f32x2*)&G[w][2][nt][l][0] = f32x2{ah[nt][0], ah[nt][1]};
      }
    }
    float vz = G[w][0][ntg][col16][rg];
    float vr = G[w][1][ntg][col16][rg];
    float vh = G[w][2][ntg][col16][rg];

    // ---- gate: 1 output per lane ----
    float xz = __uint_as_float((uint32_t)x0 << 16);
    float xr = __uint_as_float((uint32_t)x1 << 16);
    float xh = __uint_as_float((uint32_t)x2 << 16);

    float z_  = fast_rcp(1.0f + fast_exp2(fmaf(vz, -L2E, xz)));
    float rgt = fast_rcp(1.0f + fast_exp2(fmaf(vr, -L2E, xr)));
    float th  = tanh_(fmaf(rgt, vh + chv, xh));
    float hn  = fmaf(z_, hp - th, th);
    hp = hn;

    // next-step A-frag write + output store (store stays in flight)
    *(u16*)(hbbase + (hoff ^ 1024) + wb_off) = f2bf(hn);
    out[oo] = hn;
    oo += 256u;

    hoff ^= 1024;
    // light barrier: LDS ordering only; do NOT drain vmcnt (out stores)
    asm volatile("s_waitcnt lgkmcnt(0)" ::: "memory");
    __builtin_amdgcn_s_barrier();
  }

  // h_last
  out[16777216u + (uint32_t)b * 256u + (uint32_t)cg] = hp;
}

extern "C" void kernel_launch(void* const* d_in, const int* in_sizes, int n_in,
                              void* d_out, int out_size, void* d_ws, size_t ws_size,
                              hipStream_t stream) {
  const float* X  = (const float*)d_in[0];
  const float* h0 = (const float*)d_in[1];
  const float* Wz = (const float*)d_in[2];
  const float* Wr = (const float*)d_in[3];
  const float* Wh = (const float*)d_in[4];
  const float* bz = (const float*)d_in[5];
  const float* br = (const float*)d_in[6];
  const float* bh = (const float*)d_in[7];
  const float* Uz = (const float*)d_in[8];
  const float* Ur = (const float*)d_in[9];
  const float* Uh = (const float*)d_in[10];
  const float* cz = (const float*)d_in[11];
  const float* cr = (const float*)d_in[12];
  const float* ch = (const float*)d_in[13];

  char*  ws    = (char*)d_ws;
  u16*   wfrag = (u16*)ws;
  float* wbias = (float*)(ws + WS_BIAS_OFF);
  u16*   xbuf  = (u16*)(ws + WS_X_OFF);
  float* out   = (float*)d_out;

  k_prep<<<193, 256, 0, stream>>>(Wz, Wr, Wh, Uz, Ur, Uh, bz, br, bh, cz, cr, ch,
                                  wfrag, wbias);
  k_proj<<<1024, 256, 0, stream>>>(X, wfrag, wbias, xbuf);
  k_rnn<<<32, 512, 0, stream>>>(wfrag, xbuf, h0, ch, out);
}